// Round 2
// 736.618 us; speedup vs baseline: 1.2141x; 1.2141x over previous
//
#include <hip/hip_runtime.h>
#include <float.h>
#include <math.h>

#define Bdim 64
#define Qdim 32
#define Kdim 100
#define QK   (Qdim*Kdim)        // 3200
#define ROWLEN (Bdim*Kdim)      // 6400 floats per softmax row
#define ROWV  (ROWLEN/4)        // 1600 float4 per row
#define MAIN_BLOCKS (Bdim*Qdim) // 2048
#define COPY_BLOCKS 16384

typedef float floatx4 __attribute__((ext_vector_type(4)));   // native clang vec — valid for nontemporal builtins

__device__ inline float wred_max(float v){ for(int o=32;o;o>>=1) v=fmaxf(v,__shfl_down(v,o)); return v; }
__device__ inline float wred_sum(float v){ for(int o=32;o;o>>=1) v+=__shfl_down(v,o); return v; }

// Fused kernel. Blocks [0, 2048): one block per (i,qq) — log_softmax row of
// 6400, atten write, per-row tail (logit_m, conf, top-k/pseudo, loss acc,
// hard argmax). Blocks [2048, 2048+COPY_BLOCKS): bulk copy conf_in->newconf
// (the tail kernel later overwrites the 64 gathered rows; ordering resolves
// the overlap, same as the previous 4-kernel version).
// Fusion overlaps the BW-bound copy with the latency/serial-bound main tail.
//
// NOTE: x_mask arrives as int32 (JAX bool -> int), NOT bytes (old R1 bug).
// NOTE: atten_o/logitm_o/pseudo_o/conf_o/newconf_o all sit at float offset
// === 1 (mod 4) from the aligned output base -> their stores cannot be
// vec4; newconf is handled with a 3-float peel so its vec stores ARE
// aligned. out_in/conf_in are buffer bases -> 16B aligned, Kdim=100 % 4 == 0
// so row-vec loads never straddle a j-segment boundary.
__global__ __launch_bounds__(256) void conloss_fused(
    const float* __restrict__ out_in, const float* __restrict__ conf_in,
    const int* __restrict__ bidx, const int* __restrict__ xmask,
    const int* __restrict__ topk_p,
    float* __restrict__ atten_o, float* __restrict__ logitm_o,
    float* __restrict__ pseudo_o, float* __restrict__ conf_o,
    float* __restrict__ newconf_o, long long nconf,
    float* __restrict__ acc, int* __restrict__ hard_o)
{
    const int tid = threadIdx.x;

    if (blockIdx.x >= MAIN_BLOCKS) {
        // ---------------- copy role ----------------
        // dst float offset 13,721,601: peel 3 floats so vec stores are 16B
        // aligned; src is then misaligned -> scalar nt loads (contiguous
        // stream, every 128B line still read exactly once).
        const long long nv = (nconf - 3) >> 2;          // float4 groups
        const float* __restrict__ s = conf_in + 3;
        float*       __restrict__ d = newconf_o + 3;    // 16B aligned
        long long v = (long long)(blockIdx.x - MAIN_BLOCKS)*256 + tid;
        const long long str = (long long)(gridDim.x - MAIN_BLOCKS)*256;
        for (; v < nv; v += str) {
            const long long b = v << 2;
            floatx4 t;
            t.x = __builtin_nontemporal_load(s + b);
            t.y = __builtin_nontemporal_load(s + b + 1);
            t.z = __builtin_nontemporal_load(s + b + 2);
            t.w = __builtin_nontemporal_load(s + b + 3);
            __builtin_nontemporal_store(t, (floatx4*)(d + b));
        }
        if (blockIdx.x == MAIN_BLOCKS) {                // head 3 + tail <4
            if (tid < 3) newconf_o[tid] = conf_in[tid];
            const long long tb = 3 + (nv << 2);
            const int tcnt = (int)(nconf - tb);
            if (tid >= 3 && tid < 3 + tcnt) {
                const long long ix = tb + (tid - 3);
                newconf_o[ix] = conf_in[ix];
            }
        }
        return;
    }

    // ---------------- main role ----------------
    const int blk = blockIdx.x;
    const int i   = blk >> 5;           // / Qdim
    const int qq  = blk & 31;           // % Qdim
    const int base_v = i*(Bdim*QK/4) + qq*(Kdim/4);   // float4 index, max ~3.3M
    const floatx4* __restrict__ out4 = (const floatx4*)out_in;

    // pass 1: vec-load row into registers, compute max.
    // 1600 vec4 / 256 threads: c=0..5 all threads, c=6 only tid<64.
    floatx4 vv[7];
    float lmax = -INFINITY;
    #pragma unroll
    for (int c = 0; c < 7; ++c) {
        if (c < 6 || tid < 64) {
            int ve = tid + c*256;
            int j = ve/25, k4 = ve - j*25;            // 25 vec4 per j-segment
            floatx4 v = out4[base_v + j*(QK/4) + k4];
            v *= (1.0f/0.07f);
            vv[c] = v;
            lmax = fmaxf(lmax, fmaxf(fmaxf(v.x, v.y), fmaxf(v.z, v.w)));
        }
    }
    __shared__ float red[4];
    __shared__ float s_max, s_lse;
    const int wid = tid >> 6, lane = tid & 63;
    float wm = wred_max(lmax);
    if (lane == 0) red[wid] = wm;
    __syncthreads();
    if (tid == 0) s_max = fmaxf(fmaxf(red[0],red[1]), fmaxf(red[2],red[3]));
    __syncthreads();
    const float m = s_max;
    float ls = 0.f;
    #pragma unroll
    for (int c = 0; c < 7; ++c) {
        if (c < 6 || tid < 64) {
            floatx4 v = vv[c];
            ls += expf(v.x-m) + expf(v.y-m) + expf(v.z-m) + expf(v.w-m);
        }
    }
    float wsum = wred_sum(ls);
    if (lane == 0) red[wid] = wsum;
    __syncthreads();
    if (tid == 0) s_lse = m + logf(red[0]+red[1]+red[2]+red[3]);
    __syncthreads();
    const float lse = s_lse;

    // pass 2: write atten (scalar nt stores: dst odd-float offset), capture
    // diagonal logit into LDS via aligned vec4 LDS store.
    __shared__ __align__(16) float sm_logit[Kdim];
    const size_t fbase = (size_t)i*(Bdim*QK) + (size_t)qq*Kdim;
    #pragma unroll
    for (int c = 0; c < 7; ++c) {
        if (c < 6 || tid < 64) {
            int ve = tid + c*256;
            int j = ve/25, k4 = ve - j*25;
            floatx4 a = vv[c] - lse;
            float* ap = atten_o + fbase + (size_t)j*QK + 4*k4;
            __builtin_nontemporal_store(a.x, ap);
            __builtin_nontemporal_store(a.y, ap+1);
            __builtin_nontemporal_store(a.z, ap+2);
            __builtin_nontemporal_store(a.w, ap+3);
            if (j == i) *(floatx4*)&sm_logit[4*k4] = a;
        }
    }
    __syncthreads();

    // per-(i,qq) tail over Kdim=100 — wave-0-parallel (was serial tid==0).
    __shared__ float sm_pseudo[Kdim], sm_lm[Kdim];
    __shared__ float s_cm, s_cs;
    __shared__ unsigned long long s_sel[2];
    const size_t ro = (size_t)i*QK + (size_t)qq*Kdim;
    const int row = bidx[i];
    if (tid < Kdim) {
        int kk = tid;
        bool xm = xmask[ro + kk] != 0;
        float pr = xm ? conf_in[(size_t)row*QK + (size_t)qq*Kdim + kk] : 0.0f;
        sm_pseudo[kk] = pr;
        float lm = xm ? sm_logit[kk] : -FLT_MAX;
        sm_lm[kk] = lm;
        logitm_o[ro + kk] = lm;
    }
    __syncthreads();
    if (tid < 64) {                      // wave 0: each lane owns kk=tid,(tid+64)
        const bool has2 = (tid + 64) < Kdim;
        // conf softmax stats (max then sum)
        float l0 = sm_lm[tid];
        float l1 = has2 ? sm_lm[tid+64] : -FLT_MAX;
        float cmv = wred_max(fmaxf(l0, l1));
        cmv = __shfl(cmv, 0);
        float es = expf(l0 - cmv) + (has2 ? expf(l1 - cmv) : 0.f);
        float csv = wred_sum(es);
        csv = __shfl(csv, 0);
        if (tid == 0) { s_cm = cmv; s_cs = csv; }
        // hard = argmax of masked conf. exp is monotone and the max-lm entry
        // never underflows (exp(0)/cs >= 1/100), so argmax(lm with -FLT_MAX
        // where masked), ties -> lower index, is equivalent.
        float av = l0; int ai = tid;
        if (has2 && l1 > av) { av = l1; ai = tid + 64; }
        for (int o = 32; o; o >>= 1) {
            float ov = __shfl_down(av, o); int oi = __shfl_down(ai, o);
            if (ov > av || (ov == av && oi < ai)) { av = ov; ai = oi; }
        }
        if (tid == 0) hard_o[i*Qdim + qq] = ai;
        // top-k: kt rounds of wave-argmax (values desc, ties -> lower index,
        // matches lax.top_k and the previous serial loop).
        float p0 = sm_pseudo[tid];
        float p1 = has2 ? sm_pseudo[tid+64] : -INFINITY;
        int kt = *topk_p; if (kt > Kdim) kt = Kdim;
        unsigned long long sel0 = 0ull, sel1 = 0ull;
        float lsum = 0.f;
        for (int t = 0; t < kt; ++t) {
            float rv = p0; int ri = tid;
            if (p1 > rv) { rv = p1; ri = tid + 64; }
            for (int o = 32; o; o >>= 1) {
                float ov = __shfl_down(rv, o); int oi = __shfl_down(ri, o);
                if (ov > rv || (ov == rv && oi < ri)) { rv = ov; ri = oi; }
            }
            const int w = __shfl(ri, 0);             // broadcast winner to wave
            if (w == tid) p0 = -INFINITY;            // remove from candidates
            if (has2 && w == tid + 64) p1 = -INFINITY;
            if (tid == 0) {                           // lane0's rv is the max
                if (w < 64) sel0 |= 1ull << w; else sel1 |= 1ull << (w - 64);
                lsum += rv * sm_logit[w];             // pseudo already 0 if masked
            }
        }
        if (tid == 0) {
            s_sel[0] = sel0; s_sel[1] = sel1;
            atomicAdd(&acc[0], lsum);
            if (((sel0 & 1ull) != 0) && (xmask[ro] != 0)) atomicAdd(&acc[1], 1.0f);
        }
    }
    __syncthreads();
    if (tid < Kdim) {
        int kk = tid;
        bool xm = xmask[ro + kk] != 0;
        float cv = xm ? expf(sm_lm[kk] - s_cm) / s_cs : 0.f;
        conf_o[ro + kk] = cv;
        bool selb = (kk < 64) ? ((s_sel[0] >> kk) & 1ull) : ((s_sel[1] >> (kk-64)) & 1ull);
        pseudo_o[ro + kk] = selb ? sm_pseudo[kk] : 0.f;
    }
}

// EMA overwrite of the 64 gathered rows (last-write-wins for duplicates),
// plus the final loss scalar (block 64). Runs after conloss_fused completes,
// so its row writes land after the bulk copy's.
__global__ __launch_bounds__(256) void conloss_tail(
    const float* __restrict__ conf_in, const int* __restrict__ bidx,
    const int* __restrict__ xmask, const int* __restrict__ hard,
    float* __restrict__ newconf_o, const float* __restrict__ acc,
    float* __restrict__ loss_o)
{
    const int i = blockIdx.x;
    if (i == Bdim) {
        if (threadIdx.x == 0)
            loss_o[0] = -acc[0] / (acc[1] + 1.1920929e-07f);  // f32 eps, *1.0
        return;
    }
    const int row = bidx[i];
    for (int ii = i+1; ii < Bdim; ++ii) if (bidx[ii] == row) return; // later write wins
    for (int e = threadIdx.x; e < QK; e += blockDim.x) {
        int qq = e / Kdim, kk = e - qq*Kdim;
        bool xm = xmask[(size_t)i*QK + e] != 0;
        float h = (xm && kk == hard[i*Qdim + qq]) ? 1.0f : 0.0f;
        newconf_o[(size_t)row*QK + e] = 0.99f*conf_in[(size_t)row*QK + e] + 0.01f*h;
    }
}

extern "C" void kernel_launch(void* const* d_in, const int* in_sizes, int n_in,
                              void* d_out, int out_size, void* d_ws, size_t ws_size,
                              hipStream_t stream) {
    const float* out_in  = (const float*)d_in[0];
    const float* conf_in = (const float*)d_in[1];
    const int*   bidx    = (const int*)d_in[2];
    const int*   xmask   = (const int*)d_in[3];
    const int*   topk    = (const int*)d_in[4];

    float* o = (float*)d_out;
    float* loss_o   = o;
    float* atten_o  = o + 1;
    float* logitm_o = atten_o + (size_t)Bdim*Bdim*Qdim*Kdim;   // +13,107,200
    float* pseudo_o = logitm_o + (size_t)Bdim*Qdim*Kdim;       // +204,800
    float* conf_o   = pseudo_o + (size_t)Bdim*Qdim*Kdim;
    float* newconf_o= conf_o   + (size_t)Bdim*Qdim*Kdim;       // float offset 13,721,601 (== 1 mod 4)

    float* acc  = (float*)d_ws;
    int*   hard = (int*)((char*)d_ws + 64);

    const long long nconf = (long long)in_sizes[1];            // 96,000,000

    hipMemsetAsync(d_ws, 0, 64, stream);
    conloss_fused<<<MAIN_BLOCKS + COPY_BLOCKS, 256, 0, stream>>>(
        out_in, conf_in, bidx, xmask, topk,
        atten_o, logitm_o, pseudo_o, conf_o,
        newconf_o, nconf, acc, hard);
    conloss_tail<<<Bdim + 1, 256, 0, stream>>>(conf_in, bidx, xmask, hard,
                                               newconf_o, acc, loss_o);
}

// Round 3
// 714.979 us; speedup vs baseline: 1.2508x; 1.0303x over previous
//
#include <hip/hip_runtime.h>
#include <float.h>
#include <math.h>

#define Bdim 64
#define Qdim 32
#define Kdim 100
#define QK   (Qdim*Kdim)        // 3200
#define MAIN_BLOCKS (Bdim*Qdim) // 2048
#define COPY_BLOCKS 16384

typedef float floatx4 __attribute__((ext_vector_type(4)));   // native clang vec — valid for nontemporal builtins

__device__ inline float wred_max(float v){ for(int o=32;o;o>>=1) v=fmaxf(v,__shfl_down(v,o)); return v; }
__device__ inline float wred_sum(float v){ for(int o=32;o;o>>=1) v+=__shfl_down(v,o); return v; }

// Single fused kernel, two block roles.
//
// Blocks [0, 2048): one block per (i,qq). log_softmax row of 6400 -> atten,
// then the per-row tail: logit_m, conf, top-k/pseudo, loss partial, hard
// argmax, AND the EMA write of this (i,qq)'s 100-float newconf segment
// (only if i is the LAST occurrence of bidx[i] -> last-write-wins, matching
// .at[bidx].set duplicate semantics of the reference / previous versions).
//
// Blocks [2048, 2048+COPY_BLOCKS): row-structured copy conf_in -> newconf
// that SKIPS all gathered rows (membership vs the 64 bidx values staged in
// LDS). Skipping makes the main-block EMA writes race-free within the one
// kernel, eliminating the separate EMA launch.
//
// Loss accumulation: per-main-block partials written unconditionally to
// workspace (no memset needed, graph-replay safe); a 1-block reducer
// produces the scalar. No global atomics.
//
// NOTE: x_mask arrives as int32 (JAX bool -> int), NOT bytes (old R1 bug).
// NOTE: atten_o/logitm_o/pseudo_o/conf_o/newconf_o all sit at float offset
// === 1 (mod 4) from the aligned output base -> vec4 stores need peeling.
// Per copied row: dst row start === 1 (mod 4), so peel 3 head floats + 1
// tail float; the middle 799 vec4 stores are 16B-aligned (src side then
// misaligned -> scalar nt loads; reads tolerate misalignment, stores don't).
__global__ __launch_bounds__(256) void conloss_fused(
    const float* __restrict__ out_in, const float* __restrict__ conf_in,
    const int* __restrict__ bidx, const int* __restrict__ xmask,
    const int* __restrict__ topk_p,
    float* __restrict__ atten_o, float* __restrict__ logitm_o,
    float* __restrict__ pseudo_o, float* __restrict__ conf_o,
    float* __restrict__ newconf_o, long long nconf,
    float* __restrict__ part_l, float* __restrict__ part_p)
{
    const int tid = threadIdx.x;

    if (blockIdx.x >= MAIN_BLOCKS) {
        // ---------------- copy role (row-structured) ----------------
        __shared__ int s_bidx[Bdim];
        if (tid < Bdim) s_bidx[tid] = bidx[tid];
        __syncthreads();
        const int nrows = (int)(nconf / QK);                // 30000
        for (int r = blockIdx.x - MAIN_BLOCKS; r < nrows; r += COPY_BLOCKS) {
            bool gathered = false;
            #pragma unroll
            for (int t = 0; t < Bdim; ++t) gathered |= (s_bidx[t] == r);
            if (gathered) continue;                         // main blocks own this row
            const float* __restrict__ sr = conf_in  + (size_t)r*QK;
            float*       __restrict__ dr = newconf_o + (size_t)r*QK;  // === 1 mod 4
            if (tid < 3)  dr[tid]  = sr[tid];               // head peel
            if (tid == 3) dr[QK-1] = sr[QK-1];              // tail peel
            // middle: 799 aligned vec4 stores at dr+3
            for (int v = tid; v < (QK-4)/4; v += 256) {     // (3200-4)/4 = 799
                const float* sp = sr + 3 + 4*v;
                floatx4 t;
                t.x = __builtin_nontemporal_load(sp);
                t.y = __builtin_nontemporal_load(sp + 1);
                t.z = __builtin_nontemporal_load(sp + 2);
                t.w = __builtin_nontemporal_load(sp + 3);
                __builtin_nontemporal_store(t, (floatx4*)(dr + 3 + 4*v));
            }
        }
        return;
    }

    // ---------------- main role ----------------
    const int blk = blockIdx.x;
    const int i   = blk >> 5;           // / Qdim
    const int qq  = blk & 31;           // % Qdim
    const int base_v = i*(Bdim*QK/4) + qq*(Kdim/4);   // float4 index
    const floatx4* __restrict__ out4 = (const floatx4*)out_in;

    // pass 1: vec-load row into registers, compute max.
    // 1600 vec4 / 256 threads: c=0..5 all threads, c=6 only tid<64.
    floatx4 vv[7];
    float lmax = -INFINITY;
    #pragma unroll
    for (int c = 0; c < 7; ++c) {
        if (c < 6 || tid < 64) {
            int ve = tid + c*256;
            int j = ve/25, k4 = ve - j*25;            // 25 vec4 per j-segment
            floatx4 v = out4[base_v + j*(QK/4) + k4];
            v *= (1.0f/0.07f);
            vv[c] = v;
            lmax = fmaxf(lmax, fmaxf(fmaxf(v.x, v.y), fmaxf(v.z, v.w)));
        }
    }
    __shared__ float red[4];
    __shared__ float s_max, s_lse;
    const int wid = tid >> 6, lane = tid & 63;
    float wm = wred_max(lmax);
    if (lane == 0) red[wid] = wm;
    __syncthreads();
    if (tid == 0) s_max = fmaxf(fmaxf(red[0],red[1]), fmaxf(red[2],red[3]));
    __syncthreads();
    const float m = s_max;
    float ls = 0.f;
    #pragma unroll
    for (int c = 0; c < 7; ++c) {
        if (c < 6 || tid < 64) {
            floatx4 v = vv[c];
            ls += expf(v.x-m) + expf(v.y-m) + expf(v.z-m) + expf(v.w-m);
        }
    }
    float wsum = wred_sum(ls);
    if (lane == 0) red[wid] = wsum;
    __syncthreads();
    if (tid == 0) s_lse = m + logf(red[0]+red[1]+red[2]+red[3]);
    __syncthreads();
    const float lse = s_lse;

    // pass 2: write atten (scalar nt stores: dst odd-float offset), capture
    // diagonal logit into LDS via aligned vec4 LDS store.
    __shared__ __align__(16) float sm_logit[Kdim];
    const size_t fbase = (size_t)i*(Bdim*QK) + (size_t)qq*Kdim;
    #pragma unroll
    for (int c = 0; c < 7; ++c) {
        if (c < 6 || tid < 64) {
            int ve = tid + c*256;
            int j = ve/25, k4 = ve - j*25;
            floatx4 a = vv[c] - lse;
            float* ap = atten_o + fbase + (size_t)j*QK + 4*k4;
            __builtin_nontemporal_store(a.x, ap);
            __builtin_nontemporal_store(a.y, ap+1);
            __builtin_nontemporal_store(a.z, ap+2);
            __builtin_nontemporal_store(a.w, ap+3);
            if (j == i) *(floatx4*)&sm_logit[4*k4] = a;
        }
    }
    __syncthreads();

    // per-(i,qq) tail over Kdim=100 — wave-0-parallel.
    __shared__ float sm_pseudo[Kdim], sm_lm[Kdim];
    __shared__ float s_cm, s_cs;
    __shared__ unsigned long long s_sel[2];
    __shared__ int s_hard, s_ema;
    const size_t ro = (size_t)i*QK + (size_t)qq*Kdim;
    const int row = bidx[i];
    float cv0 = 0.f;                 // raw gathered confidence (kept for EMA)
    if (tid < Kdim) {
        int kk = tid;
        bool xm = xmask[ro + kk] != 0;
        cv0 = conf_in[(size_t)row*QK + (size_t)qq*Kdim + kk];
        float pr = xm ? cv0 : 0.0f;
        sm_pseudo[kk] = pr;
        float lm = xm ? sm_logit[kk] : -FLT_MAX;
        sm_lm[kk] = lm;
        logitm_o[ro + kk] = lm;
    }
    __syncthreads();
    if (tid < 64) {                      // wave 0: each lane owns kk=tid,(tid+64)
        const bool has2 = (tid + 64) < Kdim;
        // conf softmax stats (max then sum)
        float l0 = sm_lm[tid];
        float l1 = has2 ? sm_lm[tid+64] : -FLT_MAX;
        float cmv = wred_max(fmaxf(l0, l1));
        cmv = __shfl(cmv, 0);
        float es = expf(l0 - cmv) + (has2 ? expf(l1 - cmv) : 0.f);
        float csv = wred_sum(es);
        csv = __shfl(csv, 0);
        if (tid == 0) { s_cm = cmv; s_cs = csv; }
        // hard = argmax of masked conf. exp is monotone and the max-lm entry
        // never underflows, so argmax over lm (with -FLT_MAX where masked),
        // ties -> lower index, is equivalent.
        float av = l0; int ai = tid;
        if (has2 && l1 > av) { av = l1; ai = tid + 64; }
        for (int o = 32; o; o >>= 1) {
            float ov = __shfl_down(av, o); int oi = __shfl_down(ai, o);
            if (ov > av || (ov == av && oi < ai)) { av = ov; ai = oi; }
        }
        if (tid == 0) {
            s_hard = ai;
            // last-occurrence check for EMA ownership (last write wins)
            int il = 1;
            for (int ii = i+1; ii < Bdim; ++ii) if (bidx[ii] == row) { il = 0; break; }
            s_ema = il;
        }
        // top-k: kt rounds of wave-argmax (values desc, ties -> lower index,
        // matches lax.top_k).
        float p0 = sm_pseudo[tid];
        float p1 = has2 ? sm_pseudo[tid+64] : -INFINITY;
        int kt = *topk_p; if (kt > Kdim) kt = Kdim;
        unsigned long long sel0 = 0ull, sel1 = 0ull;
        float lsum = 0.f;
        for (int t = 0; t < kt; ++t) {
            float rv = p0; int ri = tid;
            if (p1 > rv) { rv = p1; ri = tid + 64; }
            for (int o = 32; o; o >>= 1) {
                float ov = __shfl_down(rv, o); int oi = __shfl_down(ri, o);
                if (ov > rv || (ov == rv && oi < ri)) { rv = ov; ri = oi; }
            }
            const int w = __shfl(ri, 0);             // broadcast winner to wave
            if (w == tid) p0 = -INFINITY;            // remove from candidates
            if (has2 && w == tid + 64) p1 = -INFINITY;
            if (tid == 0) {                           // lane0's rv is the max
                if (w < 64) sel0 |= 1ull << w; else sel1 |= 1ull << (w - 64);
                lsum += rv * sm_logit[w];             // pseudo already 0 if masked
            }
        }
        if (tid == 0) {
            s_sel[0] = sel0; s_sel[1] = sel1;
            // unconditional partial write -> no memset, no atomics
            part_l[blk] = lsum;
            part_p[blk] = (((sel0 & 1ull) != 0) && (xmask[ro] != 0)) ? 1.0f : 0.0f;
        }
    }
    __syncthreads();
    if (tid < Kdim) {
        int kk = tid;
        bool xm = xmask[ro + kk] != 0;
        float cvs = xm ? expf(sm_lm[kk] - s_cm) / s_cs : 0.f;
        conf_o[ro + kk] = cvs;
        bool selb = (kk < 64) ? ((s_sel[0] >> kk) & 1ull) : ((s_sel[1] >> (kk-64)) & 1ull);
        pseudo_o[ro + kk] = selb ? sm_pseudo[kk] : 0.f;
        if (s_ema) {   // EMA write: copy role skips this row, so no race
            float h = (xm && kk == s_hard) ? 1.0f : 0.0f;
            newconf_o[(size_t)row*QK + (size_t)qq*Kdim + kk] = 0.99f*cv0 + 0.01f*h;
        }
    }
}

// 1-block reducer: sums the 2048 per-block partials into the loss scalar.
__global__ __launch_bounds__(256) void conloss_loss(
    const float* __restrict__ part_l, const float* __restrict__ part_p,
    float* __restrict__ loss_o)
{
    const int tid = threadIdx.x;
    float a = 0.f, b = 0.f;
    for (int t = tid; t < MAIN_BLOCKS; t += 256) { a += part_l[t]; b += part_p[t]; }
    __shared__ float ra[4], rb[4];
    const int wid = tid >> 6, lane = tid & 63;
    float wa = wred_sum(a), wb = wred_sum(b);
    if (lane == 0) { ra[wid] = wa; rb[wid] = wb; }
    __syncthreads();
    if (tid == 0) {
        float s = ra[0]+ra[1]+ra[2]+ra[3];
        float c = rb[0]+rb[1]+rb[2]+rb[3];
        loss_o[0] = -s / (c + 1.1920929e-07f);   // f32 eps, * BASE_TEMPERATURE(1.0)
    }
}

extern "C" void kernel_launch(void* const* d_in, const int* in_sizes, int n_in,
                              void* d_out, int out_size, void* d_ws, size_t ws_size,
                              hipStream_t stream) {
    const float* out_in  = (const float*)d_in[0];
    const float* conf_in = (const float*)d_in[1];
    const int*   bidx    = (const int*)d_in[2];
    const int*   xmask   = (const int*)d_in[3];
    const int*   topk    = (const int*)d_in[4];

    float* o = (float*)d_out;
    float* loss_o   = o;
    float* atten_o  = o + 1;
    float* logitm_o = atten_o + (size_t)Bdim*Bdim*Qdim*Kdim;   // +13,107,200
    float* pseudo_o = logitm_o + (size_t)Bdim*Qdim*Kdim;       // +204,800
    float* conf_o   = pseudo_o + (size_t)Bdim*Qdim*Kdim;
    float* newconf_o= conf_o   + (size_t)Bdim*Qdim*Kdim;       // float offset 13,721,601 (== 1 mod 4)

    float* part_l = (float*)d_ws;                  // 2048 floats
    float* part_p = part_l + MAIN_BLOCKS;          // 2048 floats (16 KB total)

    const long long nconf = (long long)in_sizes[1];            // 96,000,000 floats

    conloss_fused<<<MAIN_BLOCKS + COPY_BLOCKS, 256, 0, stream>>>(
        out_in, conf_in, bidx, xmask, topk,
        atten_o, logitm_o, pseudo_o, conf_o,
        newconf_o, nconf, part_l, part_p);
    conloss_loss<<<1, 256, 0, stream>>>(part_l, part_p, loss_o);
}